// Round 1
// baseline (161.730 us; speedup 1.0000x reference)
//
#include <hip/hip_runtime.h>

// Problem constants (match reference)
constexpr int Bb  = 4;
constexpr int C   = 64;
constexpr int H   = 128;
constexpr int W   = 128;
constexpr int K   = 5;
constexpr int LOC = 2;
constexpr int KK  = K * K;        // 25
constexpr int CKK = C * KK;       // 1600
constexpr int HW  = H * W;        // 16384
constexpr int N   = Bb * C * HW;  // 4194304 elements per output tensor
constexpr int BHW = Bb * HW;      // 65536

// Workspace layout (in 4-byte words)
constexpr int OFF_S    = 0;                  // S[BHW]      channel sums
constexpr int OFF_M    = BHW;                // M[BHW]      max-act (box sum, clamped)
constexpr int OFF_CNT  = 2 * BHW;            // cnt[64]     nnz per out channel (int)
constexpr int OFF_WSUM = 2 * BHW + 64;       // wsum[64]    row sums of W
constexpr int OFF_RMAX = 2 * BHW + 128;      // rowmax[Bb*C]
constexpr int OFF_EIDX = 2 * BHW + 384;      // eidx[C*CKK] (int)
constexpr int OFF_EVAL = OFF_EIDX + C * CKK; // eval[C*CKK]
// total = 2*65536 + 384 + 2*102400 = 336256 words = 1,345,024 bytes

__device__ __forceinline__ float atomicMaxFloat(float* addr, float value) {
    // Works for mixed signs given init to -inf: nonneg floats order like signed
    // ints; negative floats order reversed as unsigned ints.
    if (value >= 0.0f)
        return __int_as_float(atomicMax((int*)addr, __float_as_int(value)));
    else
        return __uint_as_float(atomicMin((unsigned int*)addr, __float_as_uint(value)));
}

// Zero/neg-inf init of the small control arrays (ws is poisoned 0xAA each call).
__global__ void k_init(int* cnt, float* rowmax) {
    int t = threadIdx.x;
    if (t < 64) cnt[t] = 0;          // will be overwritten by sparsify anyway
    if (t < Bb * C) rowmax[t] = -INFINITY;
}

// Compact nonzero weights per output channel; also row sums.
__global__ void k_sparsify(const float* __restrict__ wgt, int* __restrict__ cnt,
                           float* __restrict__ wsum, int* __restrict__ eidx,
                           float* __restrict__ evals) {
    __shared__ int scnt;
    __shared__ float red[256];
    const int o = blockIdx.x;
    if (threadIdx.x == 0) scnt = 0;
    __syncthreads();
    float s = 0.0f;
    for (int k = threadIdx.x; k < CKK; k += 256) {
        float v = wgt[o * CKK + k];
        s += v;
        if (v != 0.0f) {
            int p = atomicAdd(&scnt, 1);
            eidx[o * CKK + p]  = k;
            evals[o * CKK + p] = v;
        }
    }
    red[threadIdx.x] = s;
    __syncthreads();
    for (int st = 128; st > 0; st >>= 1) {
        if (threadIdx.x < st) red[threadIdx.x] += red[threadIdx.x + st];
        __syncthreads();
    }
    if (threadIdx.x == 0) { cnt[o] = scnt; wsum[o] = red[0]; }
}

// S[b,h,w] = sum_c x[b,c,h,w]
__global__ void k_chansum(const float* __restrict__ x, float* __restrict__ S) {
    int i = blockIdx.x * 256 + threadIdx.x;   // i in [0, BHW)
    int b = i / HW;
    int p = i % HW;
    const float* px = x + (size_t)b * C * HW + p;
    float s = 0.0f;
#pragma unroll
    for (int c = 0; c < C; ++c) s += px[c * HW];
    S[i] = s;
}

// M[b,h,w] = max(box5x5(S), K)
__global__ void k_box(const float* __restrict__ S, float* __restrict__ M) {
    int i = blockIdx.x * 256 + threadIdx.x;   // i in [0, BHW)
    int b = i / HW;
    int p = i % HW;
    int h = p / W, w = p % W;
    float s = 0.0f;
    for (int j = 0; j < K; ++j) {
        int hh = h + j - LOC;
        if (hh < 0 || hh >= H) continue;
        for (int kk = 0; kk < K; ++kk) {
            int ww = w + kk - LOC;
            if (ww < 0 || ww >= W) continue;
            s += S[b * HW + hh * W + ww];
        }
    }
    M[i] = fmaxf(s, (float)K);
}

// x_lateral via sparse gather; also per-(b,o) running max of xn_pre.
__global__ void k_conv(const float* __restrict__ x, const int* __restrict__ cnt,
                       const float* __restrict__ wsum, const int* __restrict__ eidx,
                       const float* __restrict__ evals, const float* __restrict__ M,
                       float* __restrict__ out0, float* __restrict__ rowmax) {
    int idx = blockIdx.x * 256 + threadIdx.x;  // [0, N); one (b,o) per block (256 | HW)
    int w = idx % W;
    int h = (idx / W) % H;
    int o = (idx / HW) % C;
    int b = idx / (C * HW);
    int n = cnt[o];
    float acc = 0.0f;
    for (int e = 0; e < n; ++e) {
        int k  = eidx[o * CKK + e];
        float v = evals[o * CKK + e];
        int c = k / KK, r = k % KK, j = r / K, kk = r % K;
        int hh = h + j - LOC, ww = w + kk - LOC;
        if (hh >= 0 && hh < H && ww >= 0 && ww < W)
            acc += v * x[((size_t)(b * C + c) * H + hh) * W + ww];
    }
    out0[idx] = acc;
    float t = acc / M[b * HW + h * W + w] / (1e-10f + wsum[o]);
    __shared__ float red[256];
    red[threadIdx.x] = t;
    __syncthreads();
    for (int st = 128; st > 0; st >>= 1) {
        if (threadIdx.x < st) red[threadIdx.x] = fmaxf(red[threadIdx.x], red[threadIdx.x + st]);
        __syncthreads();
    }
    if (threadIdx.x == 0) atomicMaxFloat(&rowmax[b * C + o], red[0]);
}

// xn and binarized output.
__global__ void k_final(const float* __restrict__ out0, const float* __restrict__ M,
                        const float* __restrict__ wsum, const float* __restrict__ rowmax,
                        float* __restrict__ out1, float* __restrict__ out2) {
    int idx = blockIdx.x * 256 + threadIdx.x;
    int p = idx % HW;
    int o = (idx / HW) % C;
    int b = idx / (C * HW);
    float xn = out0[idx] / M[b * HW + p] / (1e-10f + wsum[o]) / (1e-10f + rowmax[b * C + o]);
    out1[idx] = xn;
    out2[idx] = (xn * xn * xn >= 0.5f) ? 1.0f : 0.0f;
}

extern "C" void kernel_launch(void* const* d_in, const int* in_sizes, int n_in,
                              void* d_out, int out_size, void* d_ws, size_t ws_size,
                              hipStream_t stream) {
    const float* x   = (const float*)d_in[0];
    const float* wgt = (const float*)d_in[1];
    float* out = (float*)d_out;
    float* wsf = (float*)d_ws;
    int*   wsi = (int*)d_ws;

    float* S      = wsf + OFF_S;
    float* M      = wsf + OFF_M;
    int*   cnt    = wsi + OFF_CNT;
    float* wsum   = wsf + OFF_WSUM;
    float* rowmax = wsf + OFF_RMAX;
    int*   eidx   = wsi + OFF_EIDX;
    float* evals  = wsf + OFF_EVAL;

    float* out0 = out;          // x_lateral
    float* out1 = out + N;      // xn
    float* out2 = out + 2 * N;  // x_lateral_bin

    k_init<<<1, 256, 0, stream>>>(cnt, rowmax);
    k_sparsify<<<C, 256, 0, stream>>>(wgt, cnt, wsum, eidx, evals);
    k_chansum<<<BHW / 256, 256, 0, stream>>>(x, S);
    k_box<<<BHW / 256, 256, 0, stream>>>(S, M);
    k_conv<<<N / 256, 256, 0, stream>>>(x, cnt, wsum, eidx, evals, M, out0, rowmax);
    k_final<<<N / 256, 256, 0, stream>>>(out0, M, wsum, rowmax, out1, out2);
}

// Round 2
// 103.793 us; speedup vs baseline: 1.5582x; 1.5582x over previous
//
#include <hip/hip_runtime.h>

// Problem constants (match reference)
constexpr int Bb  = 4;
constexpr int C   = 64;
constexpr int H   = 128;
constexpr int Wd  = 128;
constexpr int K   = 5;
constexpr int LOC = 2;
constexpr int KK  = K * K;        // 25
constexpr int CKK = C * KK;       // 1600
constexpr int HW  = H * Wd;       // 16384
constexpr int N   = Bb * C * HW;  // 4194304 per output tensor
constexpr int BHW = Bb * HW;      // 65536

// ws layout (floats): S[BHW], M[BHW]
__device__ __forceinline__ float frcp(float x) { return __builtin_amdgcn_rcpf(x); }

// S[b,h,w] = sum_c x[b,c,h,w].  256 blocks x 256 threads, 1 px/thread,
// 64 fully-coalesced independent loads per thread.
__global__ void k_chansum(const float* __restrict__ x, float* __restrict__ S) {
    int i = blockIdx.x * 256 + threadIdx.x;   // [0, BHW)
    int b = i >> 14;            // / HW
    int p = i & (HW - 1);
    const float* px = x + (size_t)b * C * HW + p;
    float s = 0.0f;
#pragma unroll
    for (int c = 0; c < C; ++c) s += px[c * HW];
    S[i] = s;
}

// M[b,h,w] = max(box5x5(S), K).  S is 256 KB -> L2-resident.
__global__ void k_box(const float* __restrict__ S, float* __restrict__ M) {
    int i = blockIdx.x * 256 + threadIdx.x;
    int b = i >> 14;
    int p = i & (HW - 1);
    int h = p >> 7, w = p & 127;
    const float* Sb = S + b * HW;
    float s = 0.0f;
#pragma unroll
    for (int j = 0; j < K; ++j) {
        int hh = h + j - LOC;
        if ((unsigned)hh >= (unsigned)H) continue;
        const float* row = Sb + hh * Wd;
#pragma unroll
        for (int kk = 0; kk < K; ++kk) {
            int ww = w + kk - LOC;
            if ((unsigned)ww < (unsigned)Wd) s += row[ww];
        }
    }
    M[i] = fmaxf(s, (float)K);
}

// One block per (b,o) plane: sparsify W row into LDS, sparse-gather conv,
// write out0, keep t = acc/(M*(1e-10+wsum)) in registers, in-block plane max,
// then write out1 (xn) and out2 (binarized). No global atomics, no out0 re-read.
__global__ void __launch_bounds__(512, 1) k_main(
    const float* __restrict__ x, const float* __restrict__ wgt,
    const float* __restrict__ M, float* __restrict__ out0,
    float* __restrict__ out1, float* __restrict__ out2) {
    __shared__ int   s_k[CKK];
    __shared__ float s_v[CKK];
    __shared__ int   s_cnt;
    __shared__ float s_wsum;
    __shared__ float s_red[8];
    __shared__ float s_rinv;

    const int tid = threadIdx.x;
    const int plane = blockIdx.x;        // b*C + o
    const int o = plane & (C - 1);
    const int b = plane >> 6;

    if (tid == 0) { s_cnt = 0; s_wsum = 0.0f; }
    __syncthreads();

    // Compact nonzero taps of W row o into LDS (zeros contribute 0 to wsum).
    const float* wrow = wgt + o * CKK;
    for (int k = tid; k < CKK; k += 512) {
        float v = wrow[k];
        if (v != 0.0f) {
            int pos = atomicAdd(&s_cnt, 1);
            s_k[pos] = k;
            s_v[pos] = v;
            atomicAdd(&s_wsum, v);
        }
    }
    __syncthreads();
    const int   n   = s_cnt;
    const float rws = frcp(1e-10f + s_wsum);

    const float* xb = x + (size_t)b * C * HW;
    float* o0 = out0 + (size_t)plane * HW;
    float* o1 = out1 + (size_t)plane * HW;
    float* o2 = out2 + (size_t)plane * HW;
    const float* Mb = M + b * HW;

    float4 t[8];
    float lmax = -INFINITY;
#pragma unroll
    for (int it = 0; it < 8; ++it) {
        const int p = it * 2048 + tid * 4;   // 4 consecutive px, same row (4|Wd)
        const int h = p >> 7, w = p & 127;
        float4 acc = {0.f, 0.f, 0.f, 0.f};
        for (int e = 0; e < n; ++e) {
            const int   k = s_k[e];
            const float v = s_v[e];
            const int c  = k / KK;
            const int r  = k - c * KK;
            const int rj = r / K;
            const int dj = rj - LOC;
            const int dk = (r - rj * K) - LOC;
            const int hh = h + dj;
            if ((unsigned)hh < (unsigned)H) {
                const float* rowp = xb + c * HW + hh * Wd;
                const int wb = w + dk;
                float x0 = ((unsigned)(wb + 0) < (unsigned)Wd) ? rowp[wb + 0] : 0.f;
                float x1 = ((unsigned)(wb + 1) < (unsigned)Wd) ? rowp[wb + 1] : 0.f;
                float x2 = ((unsigned)(wb + 2) < (unsigned)Wd) ? rowp[wb + 2] : 0.f;
                float x3 = ((unsigned)(wb + 3) < (unsigned)Wd) ? rowp[wb + 3] : 0.f;
                acc.x += v * x0; acc.y += v * x1; acc.z += v * x2; acc.w += v * x3;
            }
        }
        *reinterpret_cast<float4*>(o0 + p) = acc;
        const float4 Mv = *reinterpret_cast<const float4*>(Mb + p);
        float4 tv;
        tv.x = acc.x * frcp(Mv.x) * rws;
        tv.y = acc.y * frcp(Mv.y) * rws;
        tv.z = acc.z * frcp(Mv.z) * rws;
        tv.w = acc.w * frcp(Mv.w) * rws;
        t[it] = tv;
        lmax = fmaxf(lmax, fmaxf(fmaxf(tv.x, tv.y), fmaxf(tv.z, tv.w)));
    }

    // Plane max: wave butterfly then tiny LDS combine across 8 waves.
#pragma unroll
    for (int m = 32; m > 0; m >>= 1) lmax = fmaxf(lmax, __shfl_xor(lmax, m, 64));
    if ((tid & 63) == 0) s_red[tid >> 6] = lmax;
    __syncthreads();
    if (tid == 0) {
        float r = s_red[0];
#pragma unroll
        for (int q = 1; q < 8; ++q) r = fmaxf(r, s_red[q]);
        s_rinv = frcp(1e-10f + r);
    }
    __syncthreads();
    const float rinv = s_rinv;

#pragma unroll
    for (int it = 0; it < 8; ++it) {
        const int p = it * 2048 + tid * 4;
        const float4 tv = t[it];
        float4 xn, bn;
        xn.x = tv.x * rinv; xn.y = tv.y * rinv; xn.z = tv.z * rinv; xn.w = tv.w * rinv;
        bn.x = (xn.x * xn.x * xn.x >= 0.5f) ? 1.f : 0.f;
        bn.y = (xn.y * xn.y * xn.y >= 0.5f) ? 1.f : 0.f;
        bn.z = (xn.z * xn.z * xn.z >= 0.5f) ? 1.f : 0.f;
        bn.w = (xn.w * xn.w * xn.w >= 0.5f) ? 1.f : 0.f;
        *reinterpret_cast<float4*>(o1 + p) = xn;
        *reinterpret_cast<float4*>(o2 + p) = bn;
    }
}

extern "C" void kernel_launch(void* const* d_in, const int* in_sizes, int n_in,
                              void* d_out, int out_size, void* d_ws, size_t ws_size,
                              hipStream_t stream) {
    const float* x   = (const float*)d_in[0];
    const float* wgt = (const float*)d_in[1];
    float* out = (float*)d_out;
    float* wsf = (float*)d_ws;

    float* S = wsf;          // [BHW]
    float* M = wsf + BHW;    // [BHW]

    float* out0 = out;           // x_lateral
    float* out1 = out + N;       // xn
    float* out2 = out + 2 * N;   // x_lateral_bin

    k_chansum<<<BHW / 256, 256, 0, stream>>>(x, S);
    k_box<<<BHW / 256, 256, 0, stream>>>(S, M);
    k_main<<<Bb * C, 512, 0, stream>>>(x, wgt, M, out0, out1, out2);
}

// Round 4
// 92.460 us; speedup vs baseline: 1.7492x; 1.1226x over previous
//
#include <hip/hip_runtime.h>

// Problem constants (match reference)
constexpr int Bb  = 4;
constexpr int C   = 64;
constexpr int H   = 128;
constexpr int Wd  = 128;
constexpr int K   = 5;
constexpr int LOC = 2;
constexpr int KK  = K * K;        // 25
constexpr int CKK = C * KK;       // 1600
constexpr int HW  = H * Wd;       // 16384
constexpr int N   = Bb * C * HW;  // 4194304 per output tensor

typedef float v4f __attribute__((ext_vector_type(4)));  // native vec for NT stores

__device__ __forceinline__ float frcp(float x) { return __builtin_amdgcn_rcpf(x); }
__device__ __forceinline__ void nt_store4(float* p, v4f v) {
    __builtin_nontemporal_store(v, reinterpret_cast<v4f*>(p));
}

// Fused chansum + 5x5 box + clamp: M[b,h,w] = max(box5x5(sum_c x), K).
// Block = 2 output rows of one batch (256 blocks x 256 threads).
// S for the 6-row halo strip is computed straight from x into LDS (halo
// re-reads across neighboring blocks are L2/L3 hits; HBM fetch ~= x once).
__global__ void __launch_bounds__(256) k_prep(const float* __restrict__ x,
                                              float* __restrict__ M) {
    __shared__ float S[6][Wd];
    const int t = threadIdx.x;
    const int b = blockIdx.x >> 6;
    const int strip = blockIdx.x & 63;
    const int r0 = strip * 2;              // output rows r0, r0+1

    // Phase 1: threads 0..191 compute S (channel sum) for 6 rows x 128 cols,
    // one v4f per thread; rows outside the image are zero (pad semantics).
    if (t < 192) {
        const int lr = t >> 5;             // 0..5 -> global row r0-2+lr
        const int c0 = (t & 31) * 4;
        const int gr = r0 - 2 + lr;
        v4f s = {0.f, 0.f, 0.f, 0.f};
        if ((unsigned)gr < (unsigned)H) {
            const float* p = x + (((size_t)b * C) * H + gr) * Wd + c0;
#pragma unroll
            for (int c = 0; c < C; ++c) {
                const v4f v = *reinterpret_cast<const v4f*>(p + (size_t)c * HW);
                s += v;
            }
        }
        *reinterpret_cast<v4f*>(&S[lr][c0]) = s;
    }
    __syncthreads();

    // Phase 2: each thread one output pixel (2 rows x 128 cols = 256 px).
    const int lr = t >> 7;                 // 0..1
    const int w  = t & 127;
    const int gr = r0 + lr;
    float s = 0.f;
#pragma unroll
    for (int j = 0; j < K; ++j) {
        const float* row = S[lr + j];      // global row gr + j - 2 (zeroed if OOB)
#pragma unroll
        for (int kk = 0; kk < K; ++kk) {
            const int ww = w + kk - LOC;
            if ((unsigned)ww < (unsigned)Wd) s += row[ww];
        }
    }
    M[b * HW + gr * Wd + w] = fmaxf(s, (float)K);
}

// One block per (b,o) plane, 1024 threads (16 waves/CU): sparsify W row into
// LDS, sparse-gather conv, write out0, keep t in registers, in-block plane
// max, write out1/out2. Nontemporal stores keep x/M resident in L2.
__global__ void __launch_bounds__(1024) k_main(
    const float* __restrict__ x, const float* __restrict__ wgt,
    const float* __restrict__ M, float* __restrict__ out0,
    float* __restrict__ out1, float* __restrict__ out2) {
    __shared__ int   s_k[CKK];
    __shared__ float s_v[CKK];
    __shared__ int   s_cnt;
    __shared__ float s_wsum;
    __shared__ float s_red[16];
    __shared__ float s_rinv;

    const int tid = threadIdx.x;
    const int plane = blockIdx.x;          // b*C + o
    const int o = plane & (C - 1);
    const int b = plane >> 6;

    if (tid == 0) { s_cnt = 0; s_wsum = 0.0f; }
    __syncthreads();

    const float* wrow = wgt + o * CKK;
    for (int k = tid; k < CKK; k += 1024) {
        float v = wrow[k];
        if (v != 0.0f) {
            int pos = atomicAdd(&s_cnt, 1);
            s_k[pos] = k;
            s_v[pos] = v;
            atomicAdd(&s_wsum, v);
        }
    }
    __syncthreads();
    const int   n   = s_cnt;
    const float rws = frcp(1e-10f + s_wsum);

    const float* xb = x + (size_t)b * C * HW;
    float* o0 = out0 + (size_t)plane * HW;
    float* o1 = out1 + (size_t)plane * HW;
    float* o2 = out2 + (size_t)plane * HW;
    const float* Mb = M + b * HW;

    v4f t[4];
    float lmax = -INFINITY;
#pragma unroll
    for (int it = 0; it < 4; ++it) {
        const int p = it * 4096 + tid * 4;   // 4 consecutive px, same row (4|Wd)
        const int h = p >> 7, w = p & 127;
        v4f acc = {0.f, 0.f, 0.f, 0.f};
        for (int e = 0; e < n; ++e) {
            const int   k = s_k[e];
            const float v = s_v[e];
            const int c  = k / KK;
            const int r  = k - c * KK;
            const int rj = r / K;
            const int dj = rj - LOC;
            const int dk = (r - rj * K) - LOC;
            const int hh = h + dj;
            if ((unsigned)hh < (unsigned)H) {
                const float* rowp = xb + c * HW + hh * Wd;
                const int wb = w + dk;
                float x0 = ((unsigned)(wb + 0) < (unsigned)Wd) ? rowp[wb + 0] : 0.f;
                float x1 = ((unsigned)(wb + 1) < (unsigned)Wd) ? rowp[wb + 1] : 0.f;
                float x2 = ((unsigned)(wb + 2) < (unsigned)Wd) ? rowp[wb + 2] : 0.f;
                float x3 = ((unsigned)(wb + 3) < (unsigned)Wd) ? rowp[wb + 3] : 0.f;
                acc.x += v * x0; acc.y += v * x1; acc.z += v * x2; acc.w += v * x3;
            }
        }
        nt_store4(o0 + p, acc);
        const v4f Mv = *reinterpret_cast<const v4f*>(Mb + p);
        v4f tv;
        tv.x = acc.x * frcp(Mv.x) * rws;
        tv.y = acc.y * frcp(Mv.y) * rws;
        tv.z = acc.z * frcp(Mv.z) * rws;
        tv.w = acc.w * frcp(Mv.w) * rws;
        t[it] = tv;
        lmax = fmaxf(lmax, fmaxf(fmaxf(tv.x, tv.y), fmaxf(tv.z, tv.w)));
    }

    // Plane max: wave butterfly, then LDS combine across 16 waves.
#pragma unroll
    for (int m = 32; m > 0; m >>= 1) lmax = fmaxf(lmax, __shfl_xor(lmax, m, 64));
    if ((tid & 63) == 0) s_red[tid >> 6] = lmax;
    __syncthreads();
    if (tid == 0) {
        float r = s_red[0];
#pragma unroll
        for (int q = 1; q < 16; ++q) r = fmaxf(r, s_red[q]);
        s_rinv = frcp(1e-10f + r);
    }
    __syncthreads();
    const float rinv = s_rinv;

#pragma unroll
    for (int it = 0; it < 4; ++it) {
        const int p = it * 4096 + tid * 4;
        const v4f tv = t[it];
        v4f xn, bn;
        xn = tv * rinv;
        bn.x = (xn.x * xn.x * xn.x >= 0.5f) ? 1.f : 0.f;
        bn.y = (xn.y * xn.y * xn.y >= 0.5f) ? 1.f : 0.f;
        bn.z = (xn.z * xn.z * xn.z >= 0.5f) ? 1.f : 0.f;
        bn.w = (xn.w * xn.w * xn.w >= 0.5f) ? 1.f : 0.f;
        nt_store4(o1 + p, xn);
        nt_store4(o2 + p, bn);
    }
}

extern "C" void kernel_launch(void* const* d_in, const int* in_sizes, int n_in,
                              void* d_out, int out_size, void* d_ws, size_t ws_size,
                              hipStream_t stream) {
    const float* x   = (const float*)d_in[0];
    const float* wgt = (const float*)d_in[1];
    float* out = (float*)d_out;
    float* M   = (float*)d_ws;    // [Bb*HW]

    float* out0 = out;            // x_lateral
    float* out1 = out + N;        // xn
    float* out2 = out + 2 * N;    // x_lateral_bin

    k_prep<<<Bb * 64, 256, 0, stream>>>(x, M);
    k_main<<<Bb * C, 1024, 0, stream>>>(x, wgt, M, out0, out1, out2);
}